// Round 5
// baseline (47.547 us; speedup 1.0000x reference)
//
#include <hip/hip_runtime.h>

#define BB 4
#define NTOK 2048
#define E 96
#define NH 6
#define DH 16
#define E3 288
#define MSZ (NH*DH*DH)     // 1536 floats per batch
#define SCALE 0.25f        // D^-0.5

// One fused kernel: 256 blocks (one per 32-row tile), 256 threads.
// Phase A: kv = x@[Wk|Wv]+b (weights streamed from global), M-partial atomics.
// Phase B: q = x@Wq+b (overlaps M propagation), spin on per-batch counter.
// Phase C: t2 = q.BD(SCALE*M), out = t2@Wff+bff.
__global__ __launch_bounds__(256) void k_all(const float* __restrict__ x,
                                             const float* __restrict__ Wqkv,
                                             const float* __restrict__ bqkv,
                                             const float* __restrict__ Wff,
                                             const float* __restrict__ bff,
                                             float* __restrict__ Mg,
                                             unsigned int* __restrict__ cnt,
                                             float* __restrict__ out) {
    const int b = blockIdx.x >> 6, tile = blockIdx.x & 63;
    const int n0 = tile * 32;
    const int t = threadIdx.x;
    __shared__ float xs[32 * 100];     // x tile (stride 100); reused for t2
    __shared__ float kv[32 * 196];     // K|V tile (stride 196)
    __shared__ float qs[32 * 100];     // q tile
    __shared__ float Ms[NH * DH * 17]; // scaled M, padded stride 17

    { // stage x tile: 768 float4
        const float4* src = (const float4*)(x + ((size_t)b * NTOK + n0) * E);
        float4* dst = (float4*)xs;
        for (int f = t; f < 768; f += 256) dst[(f / 24) * 25 + (f % 24)] = src[f];
    }
    __syncthreads();

    { // P-kv: 2 rows x 12 cols per thread; weights from global (L1/L2)
        const int r0 = (t >> 4) * 2, c0 = (t & 15) * 12;
        float acc0[12], acc1[12];
        {
            const float4* bq = (const float4*)(bqkv + E + c0);
            float4 b0 = bq[0], b1 = bq[1], b2 = bq[2];
            float bb[12];
            *(float4*)&bb[0] = b0; *(float4*)&bb[4] = b1; *(float4*)&bb[8] = b2;
#pragma unroll
            for (int j = 0; j < 12; j++) { acc0[j] = bb[j]; acc1[j] = bb[j]; }
        }
        const float* wp = Wqkv + E + c0;
#pragma unroll 2
        for (int e = 0; e < E; e++) {
            float w[12];
            *(float4*)&w[0] = *(const float4*)(wp + (size_t)e * E3);
            *(float4*)&w[4] = *(const float4*)(wp + (size_t)e * E3 + 4);
            *(float4*)&w[8] = *(const float4*)(wp + (size_t)e * E3 + 8);
            const float x0 = xs[r0 * 100 + e], x1 = xs[(r0 + 1) * 100 + e];
#pragma unroll
            for (int j = 0; j < 12; j++) acc0[j] += x0 * w[j];
#pragma unroll
            for (int j = 0; j < 12; j++) acc1[j] += x1 * w[j];
        }
#pragma unroll
        for (int j = 0; j < 12; j++) kv[r0 * 196 + c0 + j] = acc0[j];
#pragma unroll
        for (int j = 0; j < 12; j++) kv[(r0 + 1) * 196 + c0 + j] = acc1[j];
    }
    __syncthreads();

    { // P-M: thread owns (d1,d2) for all 6 heads; device-scope f32 atomics
        const int d1 = t >> 4, d2 = t & 15;
        float m[NH] = {0.f, 0.f, 0.f, 0.f, 0.f, 0.f};
        for (int n = 0; n < 32; n++) {
            const float* row = &kv[n * 196];
#pragma unroll
            for (int h = 0; h < NH; h++)
                m[h] += row[h * 16 + d1] * row[96 + h * 16 + d2];
        }
#pragma unroll
        for (int h = 0; h < NH; h++)
            unsafeAtomicAdd(&Mg[b * MSZ + h * 256 + d1 * 16 + d2], m[h]);
    }
    __syncthreads();
    if (t == 0) { __threadfence(); atomicAdd(&cnt[b], 1u); }

    { // P-q: 1 row x 12 cols per thread; Wq from global
        const int r = t >> 3, c0 = (t & 7) * 12;
        float acc[12];
        {
            const float4* bq = (const float4*)(bqkv + c0);
            *(float4*)&acc[0] = bq[0]; *(float4*)&acc[4] = bq[1]; *(float4*)&acc[8] = bq[2];
        }
        const float* wp = Wqkv + c0;
#pragma unroll 4
        for (int e = 0; e < E; e++) {
            float w[12];
            *(float4*)&w[0] = *(const float4*)(wp + (size_t)e * E3);
            *(float4*)&w[4] = *(const float4*)(wp + (size_t)e * E3 + 4);
            *(float4*)&w[8] = *(const float4*)(wp + (size_t)e * E3 + 8);
            const float xv = xs[r * 100 + e];
#pragma unroll
            for (int j = 0; j < 12; j++) acc[j] += xv * w[j];
        }
        float4* qd = (float4*)&qs[r * 100 + c0];
        qd[0] = *(float4*)&acc[0]; qd[1] = *(float4*)&acc[4]; qd[2] = *(float4*)&acc[8];
    }
    __syncthreads();

    // spin until all 64 blocks of this batch have published their M partials
    if (t == 0) {
        while (__hip_atomic_load(&cnt[b], __ATOMIC_ACQUIRE, __HIP_MEMORY_SCOPE_AGENT) < 64u) {}
    }
    __syncthreads();
    { // load M coherently (agent scope), scale, stash in LDS
#pragma unroll
        for (int i = 0; i < 6; i++) {
            const int o = t + i * 256;
            const int h = o >> 8, d1 = (o >> 4) & 15, d2 = o & 15;
            Ms[h * 272 + d1 * 17 + d2] =
                SCALE * __hip_atomic_load(&Mg[b * MSZ + o], __ATOMIC_RELAXED, __HIP_MEMORY_SCOPE_AGENT);
        }
    }
    __syncthreads();

    { // P-t2: t2[r][c] = sum_d1 q[r][h*16+d1] * Ms[h][d1][c&15]  -> xs region
        const int r = t >> 3, c0 = (t & 7) * 12;
        float t2v[12];
#pragma unroll
        for (int j = 0; j < 12; j++) {
            const int c = c0 + j, h = c >> 4, d2 = c & 15;
            float v = 0.f;
#pragma unroll
            for (int d1 = 0; d1 < DH; d1++)
                v += qs[r * 100 + h * 16 + d1] * Ms[h * 272 + d1 * 17 + d2];
            t2v[j] = v;
        }
#pragma unroll
        for (int j = 0; j < 12; j++) xs[r * 100 + c0 + j] = t2v[j];
    }
    __syncthreads();

    { // P-out: out = t2 @ Wff + bff; Wff from global
        const int r = t >> 3, c0 = (t & 7) * 12;
        float acc[12];
        {
            const float4* bf = (const float4*)(bff + c0);
            *(float4*)&acc[0] = bf[0]; *(float4*)&acc[4] = bf[1]; *(float4*)&acc[8] = bf[2];
        }
        const float* wp = Wff + c0;
#pragma unroll 4
        for (int e = 0; e < E; e++) {
            float w[12];
            *(float4*)&w[0] = *(const float4*)(wp + (size_t)e * E);
            *(float4*)&w[4] = *(const float4*)(wp + (size_t)e * E + 4);
            *(float4*)&w[8] = *(const float4*)(wp + (size_t)e * E + 8);
            const float tv = xs[r * 100 + e];
#pragma unroll
            for (int j = 0; j < 12; j++) acc[j] += tv * w[j];
        }
        float4* o4 = (float4*)(out + ((size_t)b * NTOK + n0 + r) * E + c0);
        o4[0] = *(float4*)&acc[0]; o4[1] = *(float4*)&acc[4]; o4[2] = *(float4*)&acc[8];
    }
}

extern "C" void kernel_launch(void* const* d_in, const int* in_sizes, int n_in,
                              void* d_out, int out_size, void* d_ws, size_t ws_size,
                              hipStream_t stream) {
    const float* x    = (const float*)d_in[0];
    const float* Wqkv = (const float*)d_in[1];
    const float* bqkv = (const float*)d_in[2];
    const float* Wff  = (const float*)d_in[3];
    const float* bff  = (const float*)d_in[4];
    float* out = (float*)d_out;
    float* Mg  = (float*)d_ws;                               // BB*MSZ floats
    unsigned int* cnt = (unsigned int*)(Mg + BB * MSZ);      // BB counters

    hipMemsetAsync(d_ws, 0, (size_t)BB * MSZ * sizeof(float) + BB * sizeof(unsigned int), stream);
    k_all<<<BB * 64, 256, 0, stream>>>(x, Wqkv, bqkv, Wff, bff, Mg, cnt, out);
}

// Round 6
// 30.848 us; speedup vs baseline: 1.5414x; 1.5414x over previous
//
#include <hip/hip_runtime.h>

#define BB 4
#define NTOK 2048
#define E 96
#define NH 6
#define DH 16
#define E3 288
#define MSZ (NH*DH*DH)     // 1536 floats per batch
#define SCALE 0.25f        // D^-0.5

// kvT float index: column c (0..191), row n (0..31); stride 36, XOR swizzle on n.
__device__ __forceinline__ int KT4(int c, int nc) {   // float index of f4 at rows nc..nc+3
    return c * 36 + (nc ^ ((c & 7) << 2));
}

// ---- K1: per 32-row tile: kv = x@[Wk|Wv]+bias, M-partial via kvT, atomics ----
__global__ __launch_bounds__(256) void k_kv(const float* __restrict__ x,
                                            const float* __restrict__ Wqkv,
                                            const float* __restrict__ bqkv,
                                            float* __restrict__ Mg) {
    const int b = blockIdx.x >> 6, tile = blockIdx.x & 63;
    const int n0 = tile * 32;
    const int t = threadIdx.x;
    __shared__ float4 xs4[800];       // x tile 32x96, stride 100 floats
    __shared__ float4 wkv4[4704];     // [Wk|Wv] 96x192, stride 196 floats; scratch later
    __shared__ float4 kvT4[1728];     // kvT 192x36 floats (col-major kv, swizzled)
    float* xs = (float*)xs4;
    float* kvT = (float*)kvT4;

    { // stage x: 768 float4
        const float4* src = (const float4*)(x + ((size_t)b * NTOK + n0) * E);
        for (int f = t; f < 768; f += 256) xs4[(f / 24) * 25 + (f % 24)] = src[f];
    }
    { // stage wkv: 4608 float4 (qkv cols 96..287)
        const float4* src = (const float4*)Wqkv;
#pragma unroll
        for (int i = 0; i < 18; i++) {
            int f = t + i * 256;
            int e = f / 48, c = f % 48;
            wkv4[e * 49 + c] = src[e * 72 + 24 + c];
        }
    }
    __syncthreads();

    // kv compute: es-split-2, 4r x 12c register tiles
    const int es = t >> 7;            // 0: e 0..47, 1: e 48..95
    const int tt = t & 127;
    const int rg = tt >> 4, cg = tt & 15;
    const int r0 = rg * 4, c0 = cg * 12;
    float acc[4][12];
#pragma unroll
    for (int i = 0; i < 4; i++)
#pragma unroll
        for (int j = 0; j < 12; j++) acc[i][j] = 0.f;

#pragma unroll
    for (int ch = 0; ch < 6; ch++) {
        const int e0 = es * 48 + ch * 8;
        float4 xr[4][2];
#pragma unroll
        for (int i = 0; i < 4; i++) {
            xr[i][0] = *(const float4*)&xs[(r0 + i) * 100 + e0];
            xr[i][1] = *(const float4*)&xs[(r0 + i) * 100 + e0 + 4];
        }
#pragma unroll
        for (int ee = 0; ee < 8; ee++) {
            const int e = e0 + ee;
            float w[12];
            *(float4*)&w[0] = wkv4[e * 49 + 3 * cg];
            *(float4*)&w[4] = wkv4[e * 49 + 3 * cg + 1];
            *(float4*)&w[8] = wkv4[e * 49 + 3 * cg + 2];
#pragma unroll
            for (int i = 0; i < 4; i++) {
                const float xv = ((const float*)&xr[i][ee >> 2])[ee & 3];
#pragma unroll
                for (int j = 0; j < 12; j++) acc[i][j] += xv * w[j];
            }
        }
    }
    __syncthreads();                  // wkv reads done -> reuse as scratch

    float4* scratch = wkv4;           // k-major: scratch[k*128 + tt], k=0..11
    if (es == 1) {
#pragma unroll
        for (int i = 0; i < 4; i++)
#pragma unroll
            for (int q = 0; q < 3; q++)
                scratch[(i * 3 + q) * 128 + tt] =
                    make_float4(acc[i][q * 4], acc[i][q * 4 + 1], acc[i][q * 4 + 2], acc[i][q * 4 + 3]);
    }
    __syncthreads();
    if (es == 0) {
        float bb[12];
        *(float4*)&bb[0] = *(const float4*)&bqkv[E + c0];
        *(float4*)&bb[4] = *(const float4*)&bqkv[E + c0 + 4];
        *(float4*)&bb[8] = *(const float4*)&bqkv[E + c0 + 8];
#pragma unroll
        for (int i = 0; i < 4; i++)
#pragma unroll
            for (int q = 0; q < 3; q++) {
                const float4 o = scratch[(i * 3 + q) * 128 + tt];
                acc[i][q * 4]     += o.x + bb[q * 4];
                acc[i][q * 4 + 1] += o.y + bb[q * 4 + 1];
                acc[i][q * 4 + 2] += o.z + bb[q * 4 + 2];
                acc[i][q * 4 + 3] += o.w + bb[q * 4 + 3];
            }
        // write kvT: one f4 per col covering rows r0..r0+3
#pragma unroll
        for (int j = 0; j < 12; j++) {
            const int c = c0 + j;
            *(float4*)&kvT[KT4(c, r0)] =
                make_float4(acc[0][j], acc[1][j], acc[2][j], acc[3][j]);
        }
    }
    __syncthreads();

    // P-M: thread = (d1,d2) for all 6 heads; f4 dot4 over n-chunks
    {
        const int d1 = t >> 4, d2 = t & 15;
        float m[NH] = {0.f, 0.f, 0.f, 0.f, 0.f, 0.f};
#pragma unroll
        for (int nc = 0; nc < 32; nc += 4) {
#pragma unroll
            for (int h = 0; h < NH; h++) {
                const float4 kf = *(const float4*)&kvT[KT4(h * 16 + d1, nc)];
                const float4 vf = *(const float4*)&kvT[KT4(96 + h * 16 + d2, nc)];
                m[h] += kf.x * vf.x + kf.y * vf.y + kf.z * vf.z + kf.w * vf.w;
            }
        }
#pragma unroll
        for (int h = 0; h < NH; h++)
            unsafeAtomicAdd(&Mg[b * MSZ + h * 256 + d1 * 16 + d2], m[h]);
    }
}

// ---- K2: per 32-row tile: q = x@Wq+bq, t2 = q.BD(SCALE*M), out = t2@Wff+bff --
__global__ __launch_bounds__(256) void k_out(const float* __restrict__ x,
                                             const float* __restrict__ Wqkv,
                                             const float* __restrict__ bqkv,
                                             const float* __restrict__ Wff,
                                             const float* __restrict__ bff,
                                             const float* __restrict__ Mg,
                                             float* __restrict__ out) {
    const int b = blockIdx.x >> 6, tile = blockIdx.x & 63;
    const int n0 = tile * 32;
    const int t = threadIdx.x;
    __shared__ float4 xs4[800];       // x tile; later t2 tile (stride 100)
    __shared__ float4 wbuf4[2400];    // Wq then Wff (96x96, stride 100)
    __shared__ float4 qs4[800];       // q tile (stride 100)
    __shared__ float4 msd4[480];      // Ms2[h][d2][d1], strides 320/20
    __shared__ float4 scratch[2304];  // e-split reduce: [esl][k*64+tt]
    float* xs = (float*)xs4;
    float* wbuf = (float*)wbuf4;
    float* qs = (float*)qs4;
    float* Ms2 = (float*)msd4;

    { // stage x
        const float4* src = (const float4*)(x + ((size_t)b * NTOK + n0) * E);
        for (int f = t; f < 768; f += 256) xs4[(f / 24) * 25 + (f % 24)] = src[f];
    }
    { // stage Wq (qkv cols 0..95)
        const float4* src = (const float4*)Wqkv;
#pragma unroll
        for (int i = 0; i < 9; i++) {
            int f = t + i * 256;
            int e = f / 24, c = f % 24;
            wbuf4[e * 25 + c] = src[e * 72 + c];
        }
    }
    { // stage Ms2: [h][d2][d1] (d1-major f4-able), scaled
#pragma unroll
        for (int i = 0; i < 6; i++) {
            const int o = t + i * 256;
            const int h = o >> 8, d1 = (o >> 4) & 15, d2 = o & 15;
            Ms2[h * 320 + d2 * 20 + d1] = SCALE * Mg[b * MSZ + o];
        }
    }
    __syncthreads();

    const int es = t >> 6;            // wave index = e-split-4
    const int tt = t & 63;
    const int rg = tt >> 3, cg = tt & 7;
    const int r0 = rg * 4, c0 = cg * 12;

    float acc[4][12];
    // ---------------- q phase ----------------
#pragma unroll
    for (int i = 0; i < 4; i++)
#pragma unroll
        for (int j = 0; j < 12; j++) acc[i][j] = 0.f;
#pragma unroll
    for (int ch = 0; ch < 3; ch++) {
        const int e0 = es * 24 + ch * 8;
        float4 xr[4][2];
#pragma unroll
        for (int i = 0; i < 4; i++) {
            xr[i][0] = *(const float4*)&xs[(r0 + i) * 100 + e0];
            xr[i][1] = *(const float4*)&xs[(r0 + i) * 100 + e0 + 4];
        }
#pragma unroll
        for (int ee = 0; ee < 8; ee++) {
            const int e = e0 + ee;
            float w[12];
            *(float4*)&w[0] = wbuf4[e * 25 + 3 * cg];
            *(float4*)&w[4] = wbuf4[e * 25 + 3 * cg + 1];
            *(float4*)&w[8] = wbuf4[e * 25 + 3 * cg + 2];
#pragma unroll
            for (int i = 0; i < 4; i++) {
                const float xv = ((const float*)&xr[i][ee >> 2])[ee & 3];
#pragma unroll
                for (int j = 0; j < 12; j++) acc[i][j] += xv * w[j];
            }
        }
    }
    __syncthreads();
    if (es > 0) {
#pragma unroll
        for (int i = 0; i < 4; i++)
#pragma unroll
            for (int q = 0; q < 3; q++)
                scratch[(es - 1) * 768 + (i * 3 + q) * 64 + tt] =
                    make_float4(acc[i][q * 4], acc[i][q * 4 + 1], acc[i][q * 4 + 2], acc[i][q * 4 + 3]);
    }
    __syncthreads();
    if (t < 64) {                     // wave0: reduce + bias -> qs
        float bb[12];
        *(float4*)&bb[0] = *(const float4*)&bqkv[c0];
        *(float4*)&bb[4] = *(const float4*)&bqkv[c0 + 4];
        *(float4*)&bb[8] = *(const float4*)&bqkv[c0 + 8];
#pragma unroll
        for (int s = 0; s < 3; s++)
#pragma unroll
            for (int i = 0; i < 4; i++)
#pragma unroll
                for (int q = 0; q < 3; q++) {
                    const float4 o = scratch[s * 768 + (i * 3 + q) * 64 + tt];
                    acc[i][q * 4]     += o.x;
                    acc[i][q * 4 + 1] += o.y;
                    acc[i][q * 4 + 2] += o.z;
                    acc[i][q * 4 + 3] += o.w;
                }
#pragma unroll
        for (int i = 0; i < 4; i++)
#pragma unroll
            for (int q = 0; q < 3; q++)
                *(float4*)&qs[(r0 + i) * 100 + c0 + q * 4] =
                    make_float4(acc[i][q * 4] + bb[q * 4], acc[i][q * 4 + 1] + bb[q * 4 + 1],
                                acc[i][q * 4 + 2] + bb[q * 4 + 2], acc[i][q * 4 + 3] + bb[q * 4 + 3]);
    } else {                          // waves 1-3: restage wbuf <- Wff
        const float4* src = (const float4*)Wff;
#pragma unroll
        for (int i = 0; i < 12; i++) {
            int f = (t - 64) + i * 192;
            int e = f / 24, c = f % 24;
            wbuf4[e * 25 + c] = src[e * 24 + c];
        }
    }
    __syncthreads();

    // ---------------- t2 phase: t2 = q . BD(Ms) -> xs region ----------------
    {
        const int r = t >> 3, tc0 = (t & 7) * 12;
        const int h0 = tc0 >> 4, h1 = (tc0 + 11) >> 4;
        float4 qa[4], qb[4];
#pragma unroll
        for (int u = 0; u < 4; u++) {
            qa[u] = *(const float4*)&qs[r * 100 + h0 * 16 + u * 4];
            qb[u] = *(const float4*)&qs[r * 100 + h1 * 16 + u * 4];
        }
        float t2v[12];
#pragma unroll
        for (int j = 0; j < 12; j++) {
            const int c = tc0 + j, h = c >> 4, d2 = c & 15;
            const float4* mrow = (const float4*)&Ms2[h * 320 + d2 * 20];
            float v = 0.f;
#pragma unroll
            for (int u = 0; u < 4; u++) {
                const float4 qv = (h == h0) ? qa[u] : qb[u];
                const float4 mf = mrow[u];
                v += qv.x * mf.x + qv.y * mf.y + qv.z * mf.z + qv.w * mf.w;
            }
            t2v[j] = v;
        }
        __syncthreads();              // xs (x) fully dead; overwrite with t2
#pragma unroll
        for (int q = 0; q < 3; q++)
            *(float4*)&xs[r * 100 + tc0 + q * 4] =
                make_float4(t2v[q * 4], t2v[q * 4 + 1], t2v[q * 4 + 2], t2v[q * 4 + 3]);
    }
    __syncthreads();

    // ---------------- out phase: out = t2 @ Wff + bff ----------------
#pragma unroll
    for (int i = 0; i < 4; i++)
#pragma unroll
        for (int j = 0; j < 12; j++) acc[i][j] = 0.f;
#pragma unroll
    for (int ch = 0; ch < 3; ch++) {
        const int e0 = es * 24 + ch * 8;
        float4 xr[4][2];
#pragma unroll
        for (int i = 0; i < 4; i++) {
            xr[i][0] = *(const float4*)&xs[(r0 + i) * 100 + e0];
            xr[i][1] = *(const float4*)&xs[(r0 + i) * 100 + e0 + 4];
        }
#pragma unroll
        for (int ee = 0; ee < 8; ee++) {
            const int e = e0 + ee;
            float w[12];
            *(float4*)&w[0] = wbuf4[e * 25 + 3 * cg];
            *(float4*)&w[4] = wbuf4[e * 25 + 3 * cg + 1];
            *(float4*)&w[8] = wbuf4[e * 25 + 3 * cg + 2];
#pragma unroll
            for (int i = 0; i < 4; i++) {
                const float xv = ((const float*)&xr[i][ee >> 2])[ee & 3];
#pragma unroll
                for (int j = 0; j < 12; j++) acc[i][j] += xv * w[j];
            }
        }
    }
    __syncthreads();
    if (es > 0) {
#pragma unroll
        for (int i = 0; i < 4; i++)
#pragma unroll
            for (int q = 0; q < 3; q++)
                scratch[(es - 1) * 768 + (i * 3 + q) * 64 + tt] =
                    make_float4(acc[i][q * 4], acc[i][q * 4 + 1], acc[i][q * 4 + 2], acc[i][q * 4 + 3]);
    }
    __syncthreads();
    if (t < 64) {                     // wave0: reduce + bff + global store
        float bb[12];
        *(float4*)&bb[0] = *(const float4*)&bff[c0];
        *(float4*)&bb[4] = *(const float4*)&bff[c0 + 4];
        *(float4*)&bb[8] = *(const float4*)&bff[c0 + 8];
#pragma unroll
        for (int s = 0; s < 3; s++)
#pragma unroll
            for (int i = 0; i < 4; i++)
#pragma unroll
                for (int q = 0; q < 3; q++) {
                    const float4 o = scratch[s * 768 + (i * 3 + q) * 64 + tt];
                    acc[i][q * 4]     += o.x;
                    acc[i][q * 4 + 1] += o.y;
                    acc[i][q * 4 + 2] += o.z;
                    acc[i][q * 4 + 3] += o.w;
                }
#pragma unroll
        for (int i = 0; i < 4; i++) {
            float* orow = out + ((size_t)b * NTOK + n0 + r0 + i) * E + c0;
#pragma unroll
            for (int q = 0; q < 3; q++)
                *(float4*)&orow[q * 4] =
                    make_float4(acc[i][q * 4] + bb[q * 4], acc[i][q * 4 + 1] + bb[q * 4 + 1],
                                acc[i][q * 4 + 2] + bb[q * 4 + 2], acc[i][q * 4 + 3] + bb[q * 4 + 3]);
        }
    }
}

extern "C" void kernel_launch(void* const* d_in, const int* in_sizes, int n_in,
                              void* d_out, int out_size, void* d_ws, size_t ws_size,
                              hipStream_t stream) {
    const float* x    = (const float*)d_in[0];
    const float* Wqkv = (const float*)d_in[1];
    const float* bqkv = (const float*)d_in[2];
    const float* Wff  = (const float*)d_in[3];
    const float* bff  = (const float*)d_in[4];
    float* out = (float*)d_out;
    float* Mg  = (float*)d_ws;                     // BB * 1536 floats

    hipMemsetAsync(Mg, 0, (size_t)BB * MSZ * sizeof(float), stream);
    k_kv<<<BB * 64, 256, 0, stream>>>(x, Wqkv, bqkv, Mg);
    k_out<<<BB * 64, 256, 0, stream>>>(x, Wqkv, bqkv, Wff, bff, Mg, out);
}